// Round 10
// baseline (116.795 us; speedup 1.0000x reference)
//
#include <hip/hip_runtime.h>
#include <hip/hip_bf16.h>

#define DEVI __device__ __forceinline__

typedef unsigned short u16;
typedef __bf16 bf16x8 __attribute__((ext_vector_type(8)));
typedef float f32x4 __attribute__((ext_vector_type(4)));

constexpr int Bn = 2, Cn = 1024, Ln = 2048, Hn = 16, Dn = 64;

DEVI u16 f2bfu(float f) { return __builtin_bit_cast(u16, __float2bfloat16(f)); }
DEVI float bfu2f(u16 u) { return __bfloat162float(__builtin_bit_cast(__hip_bfloat16, u)); }
DEVI f32x4 mfma16(bf16x8 a, bf16x8 b, f32x4 c) {
  return __builtin_amdgcn_mfma_f32_16x16x32_bf16(a, b, c, 0, 0, 0);
}
DEVI unsigned pk2(float lo, float hi) {
  return (unsigned)f2bfu(lo) | ((unsigned)f2bfu(hi) << 16);
}
// async global->LDS, 16B per lane; LDS dest base must be wave-uniform,
// HW adds lane*16. Global source is per-lane (pre-swizzled upstream).
DEVI void gld16(const u16* g, u16* l) {
  __builtin_amdgcn_global_load_lds(
      (const __attribute__((address_space(1))) unsigned*)g,
      (__attribute__((address_space(3))) unsigned*)l, 16, 0, 0);
}
// LDS bank swizzle: fold row bit3 into bank-bit2 so permuted-row reads
// (which fix row&7 to 4 values) still spread over 8 bank-groups.
DEVI int fsw(int row) { return (row & 7) ^ (((row >> 3) & 1) << 2); }

// ---------------------------------------------------------------------------
// K1: transpose x,y [B][C][L] f32 -> xT,yT [B][L][C] bf16
// grid (L/64, C/64, 4) z = which*2 + b
__global__ __launch_bounds__(256) void transpose_xy(const float* __restrict__ x,
                                                    const float* __restrict__ y,
                                                    u16* __restrict__ xT,
                                                    u16* __restrict__ yT) {
  int z = blockIdx.z;
  int which = z >> 1, b = z & 1;
  const float* src = (which ? y : x) + (size_t)b * Cn * Ln;
  u16* dst = (which ? yT : xT) + (size_t)b * Ln * Cn;
  int l0 = blockIdx.x * 64, c0 = blockIdx.y * 64;
  __shared__ float tile[64][65];
  int t = threadIdx.x;
  #pragma unroll
  for (int i = 0; i < 16; ++i) {
    int idx = i * 256 + t;
    int r = idx >> 6, cc = idx & 63;  // r: c-row, cc: l-col
    tile[r][cc] = src[(size_t)(c0 + r) * Ln + (l0 + cc)];
  }
  __syncthreads();
  // store: pack 2 bf16 per thread -> 4B/lane coalesced
  #pragma unroll
  for (int i = 0; i < 8; ++i) {
    int idx = i * 256 + t;
    int r = idx >> 5, cc = (idx & 31) * 2;  // r: l-row, cc: c-col
    unsigned pkv = pk2(tile[cc][r], tile[cc + 1][r]);
    *(unsigned*)(&dst[(size_t)(l0 + r) * Cn + (c0 + cc)]) = pkv;
  }
}

// ---------------------------------------------------------------------------
// K2: transpose Wq/Wk/Wv [H][C][D] f32 -> WT [3][H][D][C] bf16
// grid (C/64, H, 3)
__global__ __launch_bounds__(256) void transpose_w(const float* __restrict__ Wq,
                                                   const float* __restrict__ Wk,
                                                   const float* __restrict__ Wv,
                                                   u16* __restrict__ WT) {
  int c0 = blockIdx.x * 64, h = blockIdx.y, which = blockIdx.z;
  const float* src = (which == 0 ? Wq : (which == 1 ? Wk : Wv)) + (size_t)h * Cn * Dn;
  u16* dst = WT + ((size_t)which * Hn + h) * Dn * Cn;
  __shared__ float tile[64][65];
  int t = threadIdx.x;
  #pragma unroll
  for (int i = 0; i < 16; ++i) {
    int idx = i * 256 + t;
    int r = idx >> 6, cc = idx & 63;  // r: c-row, cc: d-col
    tile[r][cc] = src[(size_t)(c0 + r) * Dn + cc];
  }
  __syncthreads();
  #pragma unroll
  for (int i = 0; i < 16; ++i) {
    int idx = i * 256 + t;
    int r = idx >> 6, cc = idx & 63;  // r: d-row, cc: c-col
    dst[(size_t)r * Cn + (c0 + cc)] = f2bfu(tile[cc][r]);
  }
}

// ---------------------------------------------------------------------------
// K3: fused QKV GEMM. O[l,n] = sum_c A[l,c]*W[n,c] + bias[n]
// A bf16 [B][L][C] (xT for Q, yT for K/V); W = WT [3][1024 rows][C].
// grid (L/128, 24, B): by -> which = by>>3, hp = by&7 (heads 2hp, 2hp+1).
// 4 waves (2x2), BM=128 BN=128 BK=64. Staging via global_load_lds (16B).
// Q/K written [B][H][L][D]; V written TRANSPOSED [B][H][D][L] via smem bounce.
__global__ __launch_bounds__(256) void gemm_qkv3(const u16* __restrict__ xT,
                                                 const u16* __restrict__ yT,
                                                 const u16* __restrict__ WT,
                                                 const float* __restrict__ bq,
                                                 const float* __restrict__ bk,
                                                 const float* __restrict__ bv,
                                                 u16* __restrict__ Qb,
                                                 u16* __restrict__ Kb,
                                                 u16* __restrict__ Vt) {
  int mt = blockIdx.x, by = blockIdx.y, b = blockIdx.z;
  int which = by >> 3, hp = by & 7;
  const u16* A = (which == 0 ? xT : yT) + (size_t)b * Ln * Cn + (size_t)mt * 128 * Cn;
  const u16* Bw = WT + ((size_t)which * 1024 + (size_t)hp * 128) * Cn;
  __shared__ __align__(16) u16 smem[2 * 128 * 64];  // lA | lB; reused as 128x128 for V transpose
  u16* lA = smem;
  u16* lB = smem + 128 * 64;
  int t = threadIdx.x, wave = t >> 6, lane = t & 63;
  int wr = wave >> 1, wc = wave & 1;
  int ml = lane & 15, kg = lane >> 4;
  f32x4 acc[4][4] = {};
  for (int k0 = 0; k0 < Cn; k0 += 64) {
    __syncthreads();
    // stage A,B (each 128x64): 1024 16B-chunks each, 4 gload_lds calls/wave
    #pragma unroll
    for (int j = 0; j < 4; ++j) {
      int q = wave * 256 + j * 64 + lane;
      int row = q >> 3, p = q & 7, c16 = p ^ (row & 7);
      gld16(A + (size_t)row * Cn + k0 + c16 * 8, &lA[(wave * 256 + j * 64) * 8]);
    }
    #pragma unroll
    for (int j = 0; j < 4; ++j) {
      int q = wave * 256 + j * 64 + lane;
      int row = q >> 3, p = q & 7, c16 = p ^ (row & 7);
      gld16(Bw + (size_t)row * Cn + k0 + c16 * 8, &lB[(wave * 256 + j * 64) * 8]);
    }
    __syncthreads();
    bf16x8 af[4][2], bf[4][2];
    #pragma unroll
    for (int m = 0; m < 4; ++m) {
      int row = wr * 64 + m * 16 + ml;
      #pragma unroll
      for (int kk = 0; kk < 2; ++kk) {
        int p = (kk * 4 + kg) ^ (row & 7);
        af[m][kk] = *(const bf16x8*)(&lA[row * 64 + p * 8]);
      }
    }
    #pragma unroll
    for (int n = 0; n < 4; ++n) {
      int row = wc * 64 + n * 16 + ml;
      #pragma unroll
      for (int kk = 0; kk < 2; ++kk) {
        int p = (kk * 4 + kg) ^ (row & 7);
        bf[n][kk] = *(const bf16x8*)(&lB[row * 64 + p * 8]);
      }
    }
    __builtin_amdgcn_s_setprio(1);
    #pragma unroll
    for (int m = 0; m < 4; ++m)
      #pragma unroll
      for (int n = 0; n < 4; ++n)
        #pragma unroll
        for (int kk = 0; kk < 2; ++kk)
          acc[m][n] = mfma16(af[m][kk], bf[n][kk], acc[m][n]);
    __builtin_amdgcn_s_setprio(0);
  }
  int head = hp * 2 + wc;
  const float* bp = (which == 0 ? bq : (which == 1 ? bk : bv));
  if (which < 2) {
    u16* O = (which == 0 ? Qb : Kb) + (((size_t)b * Hn + head) * Ln + (size_t)mt * 128) * Dn;
    #pragma unroll
    for (int n = 0; n < 4; ++n) {
      float bvv = bp[head * 64 + n * 16 + ml];
      #pragma unroll
      for (int m = 0; m < 4; ++m)
        #pragma unroll
        for (int r = 0; r < 4; ++r) {
          int row = wr * 64 + m * 16 + kg * 4 + r;
          O[(size_t)row * Dn + n * 16 + ml] = f2bfu(acc[m][n][r] + bvv);
        }
    }
  } else {
    // V: transpose through smem (128 l x 128 n), write VT [B][H][D][L]
    __syncthreads();  // all waves done with lA/lB fragments
    #pragma unroll
    for (int n = 0; n < 4; ++n) {
      float bvv = bp[head * 64 + n * 16 + ml];
      int n_loc = wc * 64 + n * 16 + ml;
      int swz = (n_loc & 7) << 4;
      #pragma unroll
      for (int m = 0; m < 4; ++m) {
        int m_base = wr * 64 + m * 16 + kg * 4;
        uint2 pkd;
        pkd.x = pk2(acc[m][n][0] + bvv, acc[m][n][1] + bvv);
        pkd.y = pk2(acc[m][n][2] + bvv, acc[m][n][3] + bvv);
        *(uint2*)(&smem[n_loc * 128 + (m_base ^ swz)]) = pkd;
      }
    }
    __syncthreads();
    u16* Vbase = Vt + ((size_t)b * Hn + hp * 2) * Dn * Ln + (size_t)mt * 128;
    #pragma unroll
    for (int i = 0; i < 8; ++i) {
      int chunk = i * 256 + t;
      int n = chunk >> 4, cc = chunk & 15;
      uint4 vv = *(const uint4*)(&smem[n * 128 + (cc ^ ((n & 7) << 1)) * 8]);
      *(uint4*)(Vbase + (size_t)n * Ln + cc * 8) = vv;  // n = h2*64+d; row stride Ln
    }
  }
}

// ---------------------------------------------------------------------------
// K5: flash attention v9: deferred-PV software pipeline (T15).
// Per phase t: stage(t+1) -> vmcnt(4) -> ONE barrier -> QK(t) || softmax+PV(t-1).
// Two independent streams per wave fill MFMA/VALU latency. 4-deep K/V buffers
// make the single barrier safe: concurrent buffer touches are write(t+1),
// K(t), K(t-1), V(t-2) = distances 1,2,3 mod 4. sA/sB named states (no
// dynamic reg indexing). 4 waves: (qs,g) = 32-q slice x kv-half.
// kv-permuted QK keeps P in registers; fsw swizzle; XCD remap.
__global__ __launch_bounds__(256, 2) void flash_attn(const u16* __restrict__ Qg,
                                                     const u16* __restrict__ Kg,
                                                     const u16* __restrict__ Vtg,
                                                     u16* __restrict__ att) {
  // --- XCD-aware remap (8 XCDs, 1024 blocks, HW assigns n%8) ---
  int n = blockIdx.x + 32 * (blockIdx.y + 16 * blockIdx.z);
  int xcd = n & 7, m = n >> 3;
  int grp = xcd * 4 + (m >> 5);       // 0..31 -> (b,h)
  int qt = m & 31;
  int h = grp & 15, b = grp >> 4;

  size_t bh = (size_t)b * Hn + h;
  const u16* Qp = Qg + (bh * Ln + (size_t)qt * 64) * Dn;
  const u16* Kp = Kg + bh * Ln * Dn;
  const u16* Vp = Vtg + bh * Dn * Ln;
  int t = threadIdx.x, wave = t >> 6, lane = t & 63;
  int qs = wave & 1, g = wave >> 1;       // 32-q slice, kv-half
  int ml = lane & 15, kg = lane >> 4;
  __shared__ __align__(16) u16 Kl[4][64 * 64];   // [kv 64][d 64] fsw-swizzled
  __shared__ __align__(16) u16 Vl[4][64 * 64];   // [d 64][kv 64] fsw-swizzled

  constexpr float QS = 0.125f * 1.44269504f;  // softmax scale + log2(e) folded into Q
  bf16x8 qf[2][2];
  #pragma unroll
  for (int qg = 0; qg < 2; ++qg)
    #pragma unroll
    for (int kk = 0; kk < 2; ++kk) {
      bf16x8 raw = *(const bf16x8*)(Qp + (size_t)(qs * 32 + qg * 16 + ml) * Dn + kk * 32 + kg * 8);
      #pragma unroll
      for (int j = 0; j < 8; ++j) raw[j] = (__bf16)((float)raw[j] * QS);
      qf[qg][kk] = raw;
    }

  f32x4 ctx[2][4] = {};
  float psum[2] = {0.f, 0.f};

  // hoisted per-lane LDS element offsets (loop-invariant)
  int koff[2][2], voff[4];
  {
    #pragma unroll
    for (int nt = 0; nt < 2; ++nt) {
      int rowk = g * 32 + 8 * (ml >> 2) + 4 * nt + (ml & 3);
      #pragma unroll
      for (int kk = 0; kk < 2; ++kk)
        koff[nt][kk] = rowk * 64 + (((kk * 4 + kg) ^ fsw(rowk)) << 3);
    }
    #pragma unroll
    for (int nt = 0; nt < 4; ++nt) {
      int rowv = nt * 16 + ml;
      voff[nt] = rowv * 64 + ((((g * 4 + kg) ^ fsw(rowv))) << 3);
    }
  }
  // hoisted per-lane global stage offsets (only kv0 varies per tile)
  int row_st[2], c16_st[2];
  #pragma unroll
  for (int j = 0; j < 2; ++j) {
    int q = j * 256 + t;
    row_st[j] = q >> 3;
    c16_st[j] = ((q & 7) ^ fsw(row_st[j])) * 8;
  }

  // 256 threads stage 2 chunks each per matrix (64x64 u16 = 512 chunks)
  auto stage = [&](int buf, int kv0) {
    #pragma unroll
    for (int j = 0; j < 2; ++j)
      gld16(Kp + (size_t)(kv0 + row_st[j]) * Dn + c16_st[j],
            &Kl[buf][(j * 256 + wave * 64) * 8]);
    #pragma unroll
    for (int j = 0; j < 2; ++j)
      gld16(Vp + (size_t)row_st[j] * Ln + kv0 + c16_st[j],
            &Vl[buf][(j * 256 + wave * 64) * 8]);
  };

  // QK: builds s fresh (first MFMA uses zero C-in); K frags shared by q-groups.
  auto QK = [&](const u16* Kh, f32x4 (&s)[2][2]) {
    bf16x8 kf[2][2];
    #pragma unroll
    for (int nt = 0; nt < 2; ++nt)
      #pragma unroll
      for (int kk = 0; kk < 2; ++kk)
        kf[nt][kk] = *(const bf16x8*)(&Kh[koff[nt][kk]]);
    __builtin_amdgcn_s_setprio(1);
    #pragma unroll
    for (int nt = 0; nt < 2; ++nt)
      #pragma unroll
      for (int qg = 0; qg < 2; ++qg) {
        f32x4 z = {};
        s[qg][nt] = mfma16(kf[nt][0], qf[qg][0], z);
        s[qg][nt] = mfma16(kf[nt][1], qf[qg][1], s[qg][nt]);
      }
    __builtin_amdgcn_s_setprio(0);
  };

  // PV: softmax finish (exp2/pack/psum) + PV MFMAs for a previous tile.
  auto PV = [&](const u16* Vh, f32x4 (&s)[2][2]) {
    bf16x8 pf[2];
    #pragma unroll
    for (int qg = 0; qg < 2; ++qg) {
      f32x4 e0, e1;
      #pragma unroll
      for (int r = 0; r < 4; ++r) e0[r] = __builtin_amdgcn_exp2f(s[qg][0][r]);
      #pragma unroll
      for (int r = 0; r < 4; ++r) e1[r] = __builtin_amdgcn_exp2f(s[qg][1][r]);
      psum[qg] += (e0[0] + e0[1]) + (e0[2] + e0[3]) + (e1[0] + e1[1]) + (e1[2] + e1[3]);
      uint4 pw;
      pw.x = pk2(e0[0], e0[1]);
      pw.y = pk2(e0[2], e0[3]);
      pw.z = pk2(e1[0], e1[1]);
      pw.w = pk2(e1[2], e1[3]);
      pf[qg] = __builtin_bit_cast(bf16x8, pw);
    }
    __builtin_amdgcn_s_setprio(1);
    #pragma unroll
    for (int nt = 0; nt < 4; ++nt) {
      bf16x8 vf = *(const bf16x8*)(&Vh[voff[nt]]);
      #pragma unroll
      for (int qg = 0; qg < 2; ++qg)
        ctx[qg][nt] = mfma16(pf[qg], vf, ctx[qg][nt]);
    }
    __builtin_amdgcn_s_setprio(0);
  };

  constexpr int NT = Ln / 64;  // 32
  f32x4 sA[2][2], sB[2][2];

  // prologue: phase 0 (QK only, no PV-prev)
  stage(0, 0);
  stage(1, 64);
  asm volatile("s_waitcnt vmcnt(4)" ::: "memory");
  __builtin_amdgcn_s_barrier();
  __builtin_amdgcn_sched_barrier(0);
  QK(&Kl[0][0], sA);

  // phases 1..30 in pairs (tt odd): QK(tt)+PV(tt-1), QK(tt+1)+PV(tt)
  for (int tt = 1; tt < NT - 1; tt += 2) {
    stage((tt + 1) & 3, (tt + 1) * 64);
    asm volatile("s_waitcnt vmcnt(4)" ::: "memory");
    __builtin_amdgcn_s_barrier();
    __builtin_amdgcn_sched_barrier(0);
    QK(&Kl[tt & 3][0], sB);
    PV(&Vl[(tt - 1) & 3][0], sA);

    if (tt + 2 < NT) {
      stage((tt + 2) & 3, (tt + 2) * 64);
      asm volatile("s_waitcnt vmcnt(4)" ::: "memory");
    } else {
      asm volatile("s_waitcnt vmcnt(0)" ::: "memory");
    }
    __builtin_amdgcn_s_barrier();
    __builtin_amdgcn_sched_barrier(0);
    QK(&Kl[(tt + 1) & 3][0], sA);
    PV(&Vl[tt & 3][0], sB);
  }

  // phase 31: last QK + PV(30); then PV(31) (no more staging, buffers stable)
  asm volatile("s_waitcnt vmcnt(0)" ::: "memory");
  __builtin_amdgcn_s_barrier();
  __builtin_amdgcn_sched_barrier(0);
  QK(&Kl[(NT - 1) & 3][0], sB);
  PV(&Vl[(NT - 2) & 3][0], sA);
  PV(&Vl[(NT - 1) & 3][0], sB);

  // combine wave-pair partials (g=1 -> g=0) through dead K/V LDS
  __syncthreads();
  float* comb = (float*)&Kl[0][0];   // [qs2*qg2*16 rows][64 lanes] f32 = 16KB
  float* psA = (float*)&Vl[0][0];    // [qs2*qg2][64 lanes]
  if (g == 1) {
    #pragma unroll
    for (int qg = 0; qg < 2; ++qg) {
      #pragma unroll
      for (int nt = 0; nt < 4; ++nt)
        #pragma unroll
        for (int r = 0; r < 4; ++r)
          comb[(((qs * 2 + qg) * 16) + nt * 4 + r) * 64 + lane] = ctx[qg][nt][r];
      psA[(qs * 2 + qg) * 64 + lane] = psum[qg];
    }
  }
  __syncthreads();
  if (g == 0) {
    #pragma unroll
    for (int qg = 0; qg < 2; ++qg) {
      #pragma unroll
      for (int nt = 0; nt < 4; ++nt)
        #pragma unroll
        for (int r = 0; r < 4; ++r)
          ctx[qg][nt][r] += comb[(((qs * 2 + qg) * 16) + nt * 4 + r) * 64 + lane];
      psum[qg] += psA[(qs * 2 + qg) * 64 + lane];
      psum[qg] += __shfl_xor(psum[qg], 16);
      psum[qg] += __shfl_xor(psum[qg], 32);
    }
    #pragma unroll
    for (int qg = 0; qg < 2; ++qg) {
      float inv[4];
      #pragma unroll
      for (int r = 0; r < 4; ++r) inv[r] = 1.f / __shfl(psum[qg], kg * 4 + r);
      #pragma unroll
      for (int nt = 0; nt < 4; ++nt)
        #pragma unroll
        for (int r = 0; r < 4; ++r) {
          size_t row = (size_t)b * Ln + qt * 64 + qs * 32 + qg * 16 + kg * 4 + r;
          att[row * Cn + h * Dn + nt * 16 + ml] = f2bfu(ctx[qg][nt][r] * inv[r]);
        }
    }
  }
}

// ---------------------------------------------------------------------------
// K6: h = xT + att ; LayerNorm over C ; out f32 [B][L][C]. grid (B*L)
__global__ __launch_bounds__(256) void ln_kernel(const u16* __restrict__ att,
                                                 const u16* __restrict__ xT,
                                                 const float* __restrict__ gamma,
                                                 const float* __restrict__ beta,
                                                 float* __restrict__ out) {
  size_t row = blockIdx.x;
  const u16* ap = att + row * Cn;
  const u16* xp = xT + row * Cn;
  float* op = out + row * Cn;
  int t = threadIdx.x;
  ushort4 a4 = *(const ushort4*)(ap + t * 4);
  ushort4 xv = *(const ushort4*)(xp + t * 4);
  float h0 = bfu2f(a4.x) + bfu2f(xv.x), h1 = bfu2f(a4.y) + bfu2f(xv.y);
  float h2 = bfu2f(a4.z) + bfu2f(xv.z), h3 = bfu2f(a4.w) + bfu2f(xv.w);
  float s = h0 + h1 + h2 + h3;
  float ss = h0 * h0 + h1 * h1 + h2 * h2 + h3 * h3;
  #pragma unroll
  for (int off = 1; off < 64; off <<= 1) {
    s += __shfl_xor(s, off);
    ss += __shfl_xor(ss, off);
  }
  __shared__ float red[8];
  int wave = t >> 6, lane = t & 63;
  if (lane == 0) { red[wave] = s; red[wave + 4] = ss; }
  __syncthreads();
  s = red[0] + red[1] + red[2] + red[3];
  ss = red[4] + red[5] + red[6] + red[7];
  float mu = s * (1.f / 1024.f);
  float var = ss * (1.f / 1024.f) - mu * mu;
  float rinv = rsqrtf(var + 1e-5f);
  float4 gmv = *(const float4*)(gamma + t * 4);
  float4 bev = *(const float4*)(beta + t * 4);
  float4 o;
  o.x = (h0 - mu) * rinv * gmv.x + bev.x;
  o.y = (h1 - mu) * rinv * gmv.y + bev.y;
  o.z = (h2 - mu) * rinv * gmv.z + bev.z;
  o.w = (h3 - mu) * rinv * gmv.w + bev.w;
  *(float4*)(op + t * 4) = o;
}

// ---------------------------------------------------------------------------
extern "C" void kernel_launch(void* const* d_in, const int* in_sizes, int n_in,
                              void* d_out, int out_size, void* d_ws, size_t ws_size,
                              hipStream_t stream) {
  const float* x = (const float*)d_in[0];
  const float* y = (const float*)d_in[1];
  const float* Wq = (const float*)d_in[2];
  const float* Wk = (const float*)d_in[3];
  const float* Wv = (const float*)d_in[4];
  const float* bq = (const float*)d_in[5];
  const float* bk = (const float*)d_in[6];
  const float* bv = (const float*)d_in[7];
  const float* gamma = (const float*)d_in[8];
  const float* beta = (const float*)d_in[9];
  float* out = (float*)d_out;

  char* ws = (char*)d_ws;
  u16* xT = (u16*)(ws + 0);               // 8388608 B
  u16* yT = (u16*)(ws + 8388608);         // 8388608 B
  u16* WT = (u16*)(ws + 16777216);        // 6291456 B
  u16* Qb = (u16*)(ws + 23068672);        // 8388608 B
  u16* Kb = (u16*)(ws + 31457280);        // 8388608 B
  u16* VT = (u16*)(ws + 39845888);        // 8388608 B
  u16* att = (u16*)(ws + 48234496);       // 8388608 B (end 56623104)

  transpose_xy<<<dim3(Ln / 64, Cn / 64, 4), dim3(256), 0, stream>>>(x, y, xT, yT);
  transpose_w<<<dim3(Cn / 64, Hn, 3), dim3(256), 0, stream>>>(Wq, Wk, Wv, WT);
  gemm_qkv3<<<dim3(Ln / 128, 24, Bn), dim3(256), 0, stream>>>(xT, yT, WT, bq, bk, bv, Qb, Kb, VT);
  flash_attn<<<dim3(Ln / 64, Hn, Bn), dim3(256), 0, stream>>>(Qb, Kb, VT, att);
  ln_kernel<<<dim3(Bn * Ln), dim3(256), 0, stream>>>(att, xT, gamma, beta, out);
}

// Round 12
// 104.427 us; speedup vs baseline: 1.1184x; 1.1184x over previous
//
#include <hip/hip_runtime.h>
#include <hip/hip_bf16.h>

#define DEVI __device__ __forceinline__

typedef unsigned short u16;
typedef __bf16 bf16x8 __attribute__((ext_vector_type(8)));
typedef float f32x4 __attribute__((ext_vector_type(4)));

constexpr int Bn = 2, Cn = 1024, Ln = 2048, Hn = 16, Dn = 64;

DEVI u16 f2bfu(float f) { return __builtin_bit_cast(u16, __float2bfloat16(f)); }
DEVI float bfu2f(u16 u) { return __bfloat162float(__builtin_bit_cast(__hip_bfloat16, u)); }
DEVI f32x4 mfma16(bf16x8 a, bf16x8 b, f32x4 c) {
  return __builtin_amdgcn_mfma_f32_16x16x32_bf16(a, b, c, 0, 0, 0);
}
DEVI unsigned pk2(float lo, float hi) {
  return (unsigned)f2bfu(lo) | ((unsigned)f2bfu(hi) << 16);
}
// async global->LDS, 16B per lane; LDS dest base must be wave-uniform,
// HW adds lane*16. Global source is per-lane (pre-swizzled upstream).
DEVI void gld16(const u16* g, u16* l) {
  __builtin_amdgcn_global_load_lds(
      (const __attribute__((address_space(1))) unsigned*)g,
      (__attribute__((address_space(3))) unsigned*)l, 16, 0, 0);
}
// LDS bank swizzle: fold row bit3 into bank-bit2 so permuted-row reads
// (which fix row&7 to 4 values) still spread over 8 bank-groups.
DEVI int fsw(int row) { return (row & 7) ^ (((row >> 3) & 1) << 2); }

// ---------------------------------------------------------------------------
// K1: transpose x,y [B][C][L] f32 -> xT,yT [B][L][C] bf16
// grid (L/64, C/64, 4) z = which*2 + b
__global__ __launch_bounds__(256) void transpose_xy(const float* __restrict__ x,
                                                    const float* __restrict__ y,
                                                    u16* __restrict__ xT,
                                                    u16* __restrict__ yT) {
  int z = blockIdx.z;
  int which = z >> 1, b = z & 1;
  const float* src = (which ? y : x) + (size_t)b * Cn * Ln;
  u16* dst = (which ? yT : xT) + (size_t)b * Ln * Cn;
  int l0 = blockIdx.x * 64, c0 = blockIdx.y * 64;
  __shared__ float tile[64][65];
  int t = threadIdx.x;
  #pragma unroll
  for (int i = 0; i < 16; ++i) {
    int idx = i * 256 + t;
    int r = idx >> 6, cc = idx & 63;  // r: c-row, cc: l-col
    tile[r][cc] = src[(size_t)(c0 + r) * Ln + (l0 + cc)];
  }
  __syncthreads();
  // store: pack 2 bf16 per thread -> 4B/lane coalesced
  #pragma unroll
  for (int i = 0; i < 8; ++i) {
    int idx = i * 256 + t;
    int r = idx >> 5, cc = (idx & 31) * 2;  // r: l-row, cc: c-col
    unsigned pkv = pk2(tile[cc][r], tile[cc + 1][r]);
    *(unsigned*)(&dst[(size_t)(l0 + r) * Cn + (c0 + cc)]) = pkv;
  }
}

// ---------------------------------------------------------------------------
// K2: transpose Wq/Wk/Wv [H][C][D] f32 -> WT [3][H][D][C] bf16
// grid (C/64, H, 3)
__global__ __launch_bounds__(256) void transpose_w(const float* __restrict__ Wq,
                                                   const float* __restrict__ Wk,
                                                   const float* __restrict__ Wv,
                                                   u16* __restrict__ WT) {
  int c0 = blockIdx.x * 64, h = blockIdx.y, which = blockIdx.z;
  const float* src = (which == 0 ? Wq : (which == 1 ? Wk : Wv)) + (size_t)h * Cn * Dn;
  u16* dst = WT + ((size_t)which * Hn + h) * Dn * Cn;
  __shared__ float tile[64][65];
  int t = threadIdx.x;
  #pragma unroll
  for (int i = 0; i < 16; ++i) {
    int idx = i * 256 + t;
    int r = idx >> 6, cc = idx & 63;  // r: c-row, cc: d-col
    tile[r][cc] = src[(size_t)(c0 + r) * Dn + cc];
  }
  __syncthreads();
  #pragma unroll
  for (int i = 0; i < 16; ++i) {
    int idx = i * 256 + t;
    int r = idx >> 6, cc = idx & 63;  // r: d-row, cc: c-col
    dst[(size_t)r * Cn + (c0 + cc)] = f2bfu(tile[cc][r]);
  }
}

// ---------------------------------------------------------------------------
// K3: fused QKV GEMM, 256x256 tile. O[l,n] = sum_c A[l,c]*W[n,c] + bias[n]
// A bf16 [4096][1024] (xT flat for Q, yT for K/V); W = WT [3][1024][C].
// grid (16, 12): mt = M-block (b = mt>>3), by: which = by>>2, hp = by&3
// (4 heads per block). 512 thr, 8 waves (2M x 4N), per-wave out 128x64.
// BK=64, double-buffered 128KB LDS, global_load_lds staging, counted
// vmcnt(8) (stage(t+1) gets a full tile of compute to land; never drain 0).
// Q/K written [B][H][L][D]; V written TRANSPOSED [B][H][D][L] via LDS bounce.
__global__ __launch_bounds__(512, 2) void gemm256(const u16* __restrict__ xT,
                                                  const u16* __restrict__ yT,
                                                  const u16* __restrict__ WT,
                                                  const float* __restrict__ bq,
                                                  const float* __restrict__ bk,
                                                  const float* __restrict__ bv,
                                                  u16* __restrict__ Qb,
                                                  u16* __restrict__ Kb,
                                                  u16* __restrict__ Vt) {
  int mt = blockIdx.x, by = blockIdx.y;
  int which = by >> 2, hp = by & 3;
  int b = mt >> 3, l0 = (mt & 7) * 256;
  const u16* A = (which == 0 ? xT : yT) + (size_t)mt * 256 * Cn;
  const u16* Bw = WT + ((size_t)which * 1024 + (size_t)hp * 256) * Cn;
  __shared__ __align__(16) u16 smem[4 * 256 * 64];  // lA[2] | lB[2] = 128KB
  int t = threadIdx.x, wave = t >> 6, lane = t & 63;
  int wr = wave >> 2, wc = wave & 3;    // 2 M-waves x 4 N-waves
  int ml = lane & 15, kg = lane >> 4;
  f32x4 acc[8][4] = {};

  // stage one K-tile (A 256x64 + B 256x64) into buf: 8 gld16 per wave
  auto stage = [&](int buf, int k0) {
    u16* la = smem + buf * 16384;
    u16* lb = smem + 32768 + buf * 16384;
    #pragma unroll
    for (int j = 0; j < 4; ++j) {
      int slot = j * 512 + t;
      int row = slot >> 3, p = slot & 7, c16 = p ^ (row & 7);
      gld16(A + (size_t)row * Cn + k0 + c16 * 8, la + (j * 512 + wave * 64) * 8);
    }
    #pragma unroll
    for (int j = 0; j < 4; ++j) {
      int slot = j * 512 + t;
      int row = slot >> 3, p = slot & 7, c16 = p ^ (row & 7);
      gld16(Bw + (size_t)row * Cn + k0 + c16 * 8, lb + (j * 512 + wave * 64) * 8);
    }
  };

  stage(0, 0);
  stage(1, 64);
  asm volatile("s_waitcnt vmcnt(8)" ::: "memory");  // tile0 landed, tile1 in flight
  __builtin_amdgcn_s_barrier();
  __builtin_amdgcn_sched_barrier(0);

  constexpr int NK = Cn / 64;  // 16
  for (int tk = 0; tk < NK; ++tk) {
    int cur = tk & 1;
    if (tk >= 1) {
      if (tk + 1 < NK) {
        stage(cur ^ 1, (tk + 1) * 64);  // overwrites tile tk-1's buf (freed)
        asm volatile("s_waitcnt vmcnt(8)" ::: "memory");  // tile tk landed
      } else {
        asm volatile("s_waitcnt vmcnt(0)" ::: "memory");
      }
      __builtin_amdgcn_s_barrier();
      __builtin_amdgcn_sched_barrier(0);
    }
    const u16* La = smem + cur * 16384;
    const u16* Lb = smem + 32768 + cur * 16384;
    // B fragments: 4 n-subtiles x 2 kk (shared across all m)
    bf16x8 bf[4][2];
    #pragma unroll
    for (int n = 0; n < 4; ++n) {
      int row = wc * 64 + n * 16 + ml;
      #pragma unroll
      for (int kk = 0; kk < 2; ++kk) {
        int p = (kk * 4 + kg) ^ (row & 7);
        bf[n][kk] = *(const bf16x8*)(&Lb[row * 64 + p * 8]);
      }
    }
    // A fragments per m-pair, 16 MFMA each
    #pragma unroll
    for (int mq = 0; mq < 4; ++mq) {
      bf16x8 af[2][2];
      #pragma unroll
      for (int m2 = 0; m2 < 2; ++m2) {
        int row = wr * 128 + mq * 32 + m2 * 16 + ml;
        #pragma unroll
        for (int kk = 0; kk < 2; ++kk) {
          int p = (kk * 4 + kg) ^ (row & 7);
          af[m2][kk] = *(const bf16x8*)(&La[row * 64 + p * 8]);
        }
      }
      __builtin_amdgcn_s_setprio(1);
      #pragma unroll
      for (int m2 = 0; m2 < 2; ++m2)
        #pragma unroll
        for (int n = 0; n < 4; ++n)
          #pragma unroll
          for (int kk = 0; kk < 2; ++kk)
            acc[mq * 2 + m2][n] = mfma16(af[m2][kk], bf[n][kk], acc[mq * 2 + m2][n]);
      __builtin_amdgcn_s_setprio(0);
    }
    asm volatile("s_waitcnt lgkmcnt(0)" ::: "memory");
    __builtin_amdgcn_s_barrier();  // release buf cur (vm loads stay in flight)
  }

  int head = hp * 4 + wc;  // each wave owns one head (64 cols)
  const float* bp = (which == 0 ? bq : (which == 1 ? bk : bv));
  if (which < 2) {
    u16* O = (which == 0 ? Qb : Kb) + (((size_t)b * Hn + head) * Ln + l0) * Dn;
    #pragma unroll
    for (int n = 0; n < 4; ++n) {
      float bvv = bp[head * 64 + n * 16 + ml];
      #pragma unroll
      for (int m = 0; m < 8; ++m)
        #pragma unroll
        for (int r = 0; r < 4; ++r) {
          int row = wr * 128 + m * 16 + kg * 4 + r;
          O[(size_t)row * Dn + n * 16 + ml] = f2bfu(acc[m][n][r] + bvv);
        }
    }
  } else {
    // V: transpose through the (dead) 128KB LDS as [n_loc 256][l_loc 256]
    __syncthreads();
    #pragma unroll
    for (int n = 0; n < 4; ++n) {
      float bvv = bp[head * 64 + n * 16 + ml];
      int n_loc = wc * 64 + n * 16 + ml;
      int swz = (n_loc & 7) << 4;  // element-index XOR, bits 4-6
      #pragma unroll
      for (int m = 0; m < 8; ++m) {
        int l_base = wr * 128 + m * 16 + kg * 4;
        uint2 pkd;
        pkd.x = pk2(acc[m][n][0] + bvv, acc[m][n][1] + bvv);
        pkd.y = pk2(acc[m][n][2] + bvv, acc[m][n][3] + bvv);
        *(uint2*)(&smem[n_loc * 256 + (l_base ^ swz)]) = pkd;
      }
    }
    __syncthreads();
    u16* Vbase = Vt + (((size_t)b * Hn + hp * 4) * Dn) * Ln + l0;
    #pragma unroll
    for (int j = 0; j < 16; ++j) {
      int chunk = j * 512 + t;
      int n = chunk >> 5, lc = chunk & 31;
      uint4 vv = *(const uint4*)(&smem[n * 256 + ((lc * 8) ^ ((n & 7) << 4))]);
      *(uint4*)(Vbase + (size_t)n * Ln + lc * 8) = vv;  // n = h_loc*64+d
    }
  }
}

// ---------------------------------------------------------------------------
// K5: flash attention v8 (best measured: 51.8us): 32 q-rows per wave, K/V LDS
// fragments reused across 2 q-groups. 4 waves (256 thr): (qs,g) = 32-q slice x
// kv-half. Double-buffered K/V via global_load_lds, counted vmcnt(4), two
// barriers/tile. kv-permuted QK output keeps P in registers. fsw swizzle;
// XCD remap. out att bf16 [B][L][H*D].
__global__ __launch_bounds__(256, 4) void flash_attn(const u16* __restrict__ Qg,
                                                     const u16* __restrict__ Kg,
                                                     const u16* __restrict__ Vtg,
                                                     u16* __restrict__ att) {
  // --- XCD-aware remap (8 XCDs, 1024 blocks, HW assigns n%8) ---
  int n = blockIdx.x + 32 * (blockIdx.y + 16 * blockIdx.z);
  int xcd = n & 7, m = n >> 3;
  int grp = xcd * 4 + (m >> 5);       // 0..31 -> (b,h)
  int qt = m & 31;
  int h = grp & 15, b = grp >> 4;

  size_t bh = (size_t)b * Hn + h;
  const u16* Qp = Qg + (bh * Ln + (size_t)qt * 64) * Dn;
  const u16* Kp = Kg + bh * Ln * Dn;
  const u16* Vp = Vtg + bh * Dn * Ln;
  int t = threadIdx.x, wave = t >> 6, lane = t & 63;
  int qs = wave & 1, g = wave >> 1;       // 32-q slice, kv-half
  int ml = lane & 15, kg = lane >> 4;
  __shared__ __align__(16) u16 Kl[2][64 * 64];   // [kv 64][d 64] fsw-swizzled
  __shared__ __align__(16) u16 Vl[2][64 * 64];   // [d 64][kv 64] fsw-swizzled

  constexpr float QS = 0.125f * 1.44269504f;  // softmax scale + log2(e) folded into Q
  bf16x8 qf[2][2];
  #pragma unroll
  for (int qg = 0; qg < 2; ++qg)
    #pragma unroll
    for (int kk = 0; kk < 2; ++kk) {
      bf16x8 raw = *(const bf16x8*)(Qp + (size_t)(qs * 32 + qg * 16 + ml) * Dn + kk * 32 + kg * 8);
      #pragma unroll
      for (int j = 0; j < 8; ++j) raw[j] = (__bf16)((float)raw[j] * QS);
      qf[qg][kk] = raw;
    }

  f32x4 ctx[2][4] = {};
  float psum[2] = {0.f, 0.f};

  // hoisted per-lane LDS element offsets (loop-invariant)
  int koff[2][2], voff[4];
  {
    #pragma unroll
    for (int nt = 0; nt < 2; ++nt) {
      int rowk = g * 32 + 8 * (ml >> 2) + 4 * nt + (ml & 3);
      #pragma unroll
      for (int kk = 0; kk < 2; ++kk)
        koff[nt][kk] = rowk * 64 + (((kk * 4 + kg) ^ fsw(rowk)) << 3);
    }
    #pragma unroll
    for (int nt = 0; nt < 4; ++nt) {
      int rowv = nt * 16 + ml;
      voff[nt] = rowv * 64 + ((((g * 4 + kg) ^ fsw(rowv))) << 3);
    }
  }
  // hoisted per-lane global stage offsets (only kv0 varies per tile)
  int row_st[2], c16_st[2];
  #pragma unroll
  for (int j = 0; j < 2; ++j) {
    int q = j * 256 + t;
    row_st[j] = q >> 3;
    c16_st[j] = ((q & 7) ^ fsw(row_st[j])) * 8;
  }

  // 256 threads stage 2 chunks each per matrix (64x64 u16 = 512 chunks)
  auto stage = [&](int buf, int kv0) {
    #pragma unroll
    for (int j = 0; j < 2; ++j)
      gld16(Kp + (size_t)(kv0 + row_st[j]) * Dn + c16_st[j],
            &Kl[buf][(j * 256 + wave * 64) * 8]);
    #pragma unroll
    for (int j = 0; j < 2; ++j)
      gld16(Vp + (size_t)row_st[j] * Ln + kv0 + c16_st[j],
            &Vl[buf][(j * 256 + wave * 64) * 8]);
  };

  constexpr int NT = Ln / 64;

  auto tile = [&](int cur, int tt) {
    if (tt + 1 < NT) {
      stage(cur ^ 1, (tt + 1) * 64);  // 4 VMEM ops stay in flight across barrier
      asm volatile("s_waitcnt vmcnt(4)" ::: "memory");
    } else {
      asm volatile("s_waitcnt vmcnt(0)" ::: "memory");
    }
    __builtin_amdgcn_s_barrier();        // B: all waves' tile-tt loads landed
    __builtin_amdgcn_sched_barrier(0);
    const u16* Kh = Kl[cur];
    const u16* Vh = Vl[cur];
    // S^T = K.Q^T, kv-permuted A-rows: lane (ml,kg) reg r of subtile nt holds
    // kv = g*32 + kg*8 + nt*4 + r. K frags shared by both q-groups.
    bf16x8 kf[2][2];
    #pragma unroll
    for (int nt = 0; nt < 2; ++nt)
      #pragma unroll
      for (int kk = 0; kk < 2; ++kk)
        kf[nt][kk] = *(const bf16x8*)(&Kh[koff[nt][kk]]);
    f32x4 s[2][2] = {};
    __builtin_amdgcn_s_setprio(1);
    #pragma unroll
    for (int nt = 0; nt < 2; ++nt)
      #pragma unroll
      for (int kk = 0; kk < 2; ++kk)
        #pragma unroll
        for (int qg = 0; qg < 2; ++qg)
          s[qg][nt] = mfma16(kf[nt][kk], qf[qg][kk], s[qg][nt]);
    __builtin_amdgcn_s_setprio(0);
    // P = exp2(S), packed straight into the PV A-fragment (registers only)
    bf16x8 pf[2];
    #pragma unroll
    for (int qg = 0; qg < 2; ++qg) {
      f32x4 e0, e1;
      #pragma unroll
      for (int r = 0; r < 4; ++r) e0[r] = __builtin_amdgcn_exp2f(s[qg][0][r]);
      #pragma unroll
      for (int r = 0; r < 4; ++r) e1[r] = __builtin_amdgcn_exp2f(s[qg][1][r]);
      psum[qg] += (e0[0] + e0[1]) + (e0[2] + e0[3]) + (e1[0] + e1[1]) + (e1[2] + e1[3]);
      uint4 pw;
      pw.x = pk2(e0[0], e0[1]);
      pw.y = pk2(e0[2], e0[3]);
      pw.z = pk2(e1[0], e1[1]);
      pw.w = pk2(e1[2], e1[3]);
      pf[qg] = __builtin_bit_cast(bf16x8, pw);
    }
    // ctx += P V over this kv half; V frags shared by both q-groups
    __builtin_amdgcn_s_setprio(1);
    #pragma unroll
    for (int nt = 0; nt < 4; ++nt) {
      bf16x8 vf = *(const bf16x8*)(&Vh[voff[nt]]);
      #pragma unroll
      for (int qg = 0; qg < 2; ++qg)
        ctx[qg][nt] = mfma16(pf[qg], vf, ctx[qg][nt]);
    }
    __builtin_amdgcn_s_setprio(0);
    asm volatile("s_waitcnt lgkmcnt(0)" ::: "memory");
    __builtin_amdgcn_s_barrier();        // A: release buffer cur (no vm drain)
  };

  stage(0, 0);
  asm volatile("s_waitcnt vmcnt(0)" ::: "memory");
  __builtin_amdgcn_s_barrier();

  for (int tt = 0; tt < NT; tt += 2) {
    tile(0, tt);
    tile(1, tt + 1);
  }

  // combine wave-pair partials (g=1 -> g=0) through dead K/V LDS
  __syncthreads();
  float* comb = (float*)&Kl[0][0];   // [qs2*qg2*16 rows][64 lanes] f32 = 16KB
  float* psA = (float*)&Vl[0][0];    // [qs2*qg2][64 lanes]
  if (g == 1) {
    #pragma unroll
    for (int qg = 0; qg < 2; ++qg) {
      #pragma unroll
      for (int nt = 0; nt < 4; ++nt)
        #pragma unroll
        for (int r = 0; r < 4; ++r)
          comb[(((qs * 2 + qg) * 16) + nt * 4 + r) * 64 + lane] = ctx[qg][nt][r];
      psA[(qs * 2 + qg) * 64 + lane] = psum[qg];
    }
  }
  __syncthreads();
  if (g == 0) {
    #pragma unroll
    for (int qg = 0; qg < 2; ++qg) {
      #pragma unroll
      for (int nt = 0; nt < 4; ++nt)
        #pragma unroll
        for (int r = 0; r < 4; ++r)
          ctx[qg][nt][r] += comb[(((qs * 2 + qg) * 16) + nt * 4 + r) * 64 + lane];
      psum[qg] += psA[(qs * 2 + qg) * 64 + lane];
      psum[qg] += __shfl_xor(psum[qg], 16);
      psum[qg] += __shfl_xor(psum[qg], 32);
    }
    #pragma unroll
    for (int qg = 0; qg < 2; ++qg) {
      float inv[4];
      #pragma unroll
      for (int r = 0; r < 4; ++r) inv[r] = 1.f / __shfl(psum[qg], kg * 4 + r);
      #pragma unroll
      for (int nt = 0; nt < 4; ++nt)
        #pragma unroll
        for (int r = 0; r < 4; ++r) {
          size_t row = (size_t)b * Ln + qt * 64 + qs * 32 + qg * 16 + kg * 4 + r;
          att[row * Cn + h * Dn + nt * 16 + ml] = f2bfu(ctx[qg][nt][r] * inv[r]);
        }
    }
  }
}

// ---------------------------------------------------------------------------
// K6: h = xT + att ; LayerNorm over C ; out f32 [B][L][C]. grid (B*L)
__global__ __launch_bounds__(256) void ln_kernel(const u16* __restrict__ att,
                                                 const u16* __restrict__ xT,
                                                 const float* __restrict__ gamma,
                                                 const float* __restrict__ beta,
                                                 float* __restrict__ out) {
  size_t row = blockIdx.x;
  const u16* ap = att + row * Cn;
  const u16* xp = xT + row * Cn;
  float* op = out + row * Cn;
  int t = threadIdx.x;
  ushort4 a4 = *(const ushort4*)(ap + t * 4);
  ushort4 xv = *(const ushort4*)(xp + t * 4);
  float h0 = bfu2f(a4.x) + bfu2f(xv.x), h1 = bfu2f(a4.y) + bfu2f(xv.y);
  float h2 = bfu2f(a4.z) + bfu2f(xv.z), h3 = bfu2f(a4.w) + bfu2f(xv.w);
  float s = h0 + h1 + h2 + h3;
  float ss = h0 * h0 + h1 * h1 + h2 * h2 + h3 * h3;
  #pragma unroll
  for (int off = 1; off < 64; off <<= 1) {
    s += __shfl_xor(s, off);
    ss += __shfl_xor(ss, off);
  }
  __shared__ float red[8];
  int wave = t >> 6, lane = t & 63;
  if (lane == 0) { red[wave] = s; red[wave + 4] = ss; }
  __syncthreads();
  s = red[0] + red[1] + red[2] + red[3];
  ss = red[4] + red[5] + red[6] + red[7];
  float mu = s * (1.f / 1024.f);
  float var = ss * (1.f / 1024.f) - mu * mu;
  float rinv = rsqrtf(var + 1e-5f);
  float4 gmv = *(const float4*)(gamma + t * 4);
  float4 bev = *(const float4*)(beta + t * 4);
  float4 o;
  o.x = (h0 - mu) * rinv * gmv.x + bev.x;
  o.y = (h1 - mu) * rinv * gmv.y + bev.y;
  o.z = (h2 - mu) * rinv * gmv.z + bev.z;
  o.w = (h3 - mu) * rinv * gmv.w + bev.w;
  *(float4*)(op + t * 4) = o;
}

// ---------------------------------------------------------------------------
extern "C" void kernel_launch(void* const* d_in, const int* in_sizes, int n_in,
                              void* d_out, int out_size, void* d_ws, size_t ws_size,
                              hipStream_t stream) {
  const float* x = (const float*)d_in[0];
  const float* y = (const float*)d_in[1];
  const float* Wq = (const float*)d_in[2];
  const float* Wk = (const float*)d_in[3];
  const float* Wv = (const float*)d_in[4];
  const float* bq = (const float*)d_in[5];
  const float* bk = (const float*)d_in[6];
  const float* bv = (const float*)d_in[7];
  const float* gamma = (const float*)d_in[8];
  const float* beta = (const float*)d_in[9];
  float* out = (float*)d_out;

  char* ws = (char*)d_ws;
  u16* xT = (u16*)(ws + 0);               // 8388608 B
  u16* yT = (u16*)(ws + 8388608);         // 8388608 B
  u16* WT = (u16*)(ws + 16777216);        // 6291456 B
  u16* Qb = (u16*)(ws + 23068672);        // 8388608 B
  u16* Kb = (u16*)(ws + 31457280);        // 8388608 B
  u16* VT = (u16*)(ws + 39845888);        // 8388608 B
  u16* att = (u16*)(ws + 48234496);       // 8388608 B (end 56623104)

  transpose_xy<<<dim3(Ln / 64, Cn / 64, 4), dim3(256), 0, stream>>>(x, y, xT, yT);
  transpose_w<<<dim3(Cn / 64, Hn, 3), dim3(256), 0, stream>>>(Wq, Wk, Wv, WT);
  gemm256<<<dim3(16, 12), dim3(512), 0, stream>>>(xT, yT, WT, bq, bk, bv, Qb, Kb, VT);
  flash_attn<<<dim3(Ln / 64, Hn, Bn), dim3(256), 0, stream>>>(Qb, Kb, VT, att);
  ln_kernel<<<dim3(Bn * Ln), dim3(256), 0, stream>>>(att, xT, gamma, beta, out);
}